// Round 3
// baseline (81.058 us; speedup 1.0000x reference)
//
#include <hip/hip_runtime.h>
#include <hip/hip_bf16.h>

// Problem: B=8, C=64, H=W=64, N=4096, P=1024.
// ws layout:
//   bf16 region (elements):
//     Kt (B,N,C) @ 0          Vc (B,C,N) @ 2097152
//     Qt (B,N,C) @ 4194304    qt (B,P,C) @ 6291456
//     O1 (B,C,P) @ 6815744    (total 14.7 MB)
//   byte 16 MB: partO  f32 [b8][qb8][ks8][c64][q128]  (16 MB)
//   byte 32 MB: partML f32x2 [b8][qb8][ks8][q128]     (0.5 MB)
// ws_size = 256 MB (observed via harness fill WRITE_SIZE).

typedef float  f32x4  __attribute__((ext_vector_type(4)));
typedef __bf16 bf16x8 __attribute__((ext_vector_type(8)));
typedef __bf16 bf16x4 __attribute__((ext_vector_type(4)));

// chunk (16B) XOR swizzle within each 64-chunk (8-row) group
__device__ __forceinline__ int swz(int ch) { return ch ^ ((ch >> 3) & 7); }

// ---------------------------------------------------------------------------
// Kernel 1: four 1x1 convs (+bias), fp32, bf16 outputs in MFMA layouts.
// Grid 1024 = m*256 + b*32 + rp; block 128 thr, each thread 8o x 8n
// (64 B LDS per 64 FMA vs 48/32 before). LDS 51 KB -> 3 blocks/CU.
// ---------------------------------------------------------------------------
__global__ __launch_bounds__(128) void conv4_kernel(
    const float* __restrict__ x,
    const float* __restrict__ wq, const float* __restrict__ bq,
    const float* __restrict__ wQ, const float* __restrict__ bQ,
    const float* __restrict__ wK, const float* __restrict__ bK,
    const float* __restrict__ wV, const float* __restrict__ bV,
    __bf16* __restrict__ Kt, __bf16* __restrict__ Vc,
    __bf16* __restrict__ Qt, __bf16* __restrict__ qt)
{
  __shared__ float xs[64 * 132];
  __shared__ float wsh[64 * 68];

  const int tid = threadIdx.x;
  const int m   = blockIdx.x >> 8;
  const int b   = (blockIdx.x >> 5) & 7;
  const int rp  = blockIdx.x & 31;
  const int n0  = rp << 7;

  const float* wg = (m == 0) ? wK : (m == 1) ? wV : (m == 2) ? wQ : wq;
  const float* bg = (m == 0) ? bK : (m == 1) ? bV : (m == 2) ? bQ : bq;

  for (int i = tid; i < 64 * 32; i += 128) {
    int c = i >> 5, j = i & 31;
    *(f32x4*)&xs[c * 132 + j * 4] =
        *(const f32x4*)&x[((size_t)(b * 64 + c)) * 4096 + n0 + j * 4];
  }
  for (int i = tid; i < 1024; i += 128) {
    int o = i >> 4, c0 = (i & 15) << 2;
    f32x4 v = *(const f32x4*)&wg[o * 64 + c0];
    wsh[(c0 + 0) * 68 + o] = v[0];
    wsh[(c0 + 1) * 68 + o] = v[1];
    wsh[(c0 + 2) * 68 + o] = v[2];
    wsh[(c0 + 3) * 68 + o] = v[3];
  }
  __syncthreads();

  const int ty = tid >> 4, tx = tid & 15;   // ty 0..7 -> 8 o each

  float acc[8][8];
  {
    f32x4 bv0 = *(const f32x4*)&bg[ty * 8];
    f32x4 bv1 = *(const f32x4*)&bg[ty * 8 + 4];
#pragma unroll
    for (int j = 0; j < 8; ++j) {
#pragma unroll
      for (int i = 0; i < 4; ++i) { acc[i][j] = bv0[i]; acc[i + 4][j] = bv1[i]; }
    }
  }

#pragma unroll 4
  for (int c = 0; c < 64; ++c) {
    f32x4 wv0 = *(const f32x4*)&wsh[c * 68 + ty * 8];
    f32x4 wv1 = *(const f32x4*)&wsh[c * 68 + ty * 8 + 4];
    f32x4 xa  = *(const f32x4*)&xs[c * 132 + tx * 8];
    f32x4 xb  = *(const f32x4*)&xs[c * 132 + tx * 8 + 4];
#pragma unroll
    for (int i = 0; i < 4; ++i) {
#pragma unroll
      for (int j = 0; j < 4; ++j) {
        acc[i][j]         += wv0[i] * xa[j];
        acc[i][j + 4]     += wv0[i] * xb[j];
        acc[i + 4][j]     += wv1[i] * xa[j];
        acc[i + 4][j + 4] += wv1[i] * xb[j];
      }
    }
  }

  if (m == 0 || m == 2) {            // Kt / Qt : (B,N,C)
    __bf16* dst = (m == 0) ? Kt : Qt;
#pragma unroll
    for (int j = 0; j < 8; ++j) {
      int n = n0 + tx * 8 + j;
      bf16x8 pk;
#pragma unroll
      for (int i = 0; i < 8; ++i) pk[i] = (__bf16)acc[i][j];
      *(bf16x8*)&dst[((size_t)(b * 4096 + n)) * 64 + ty * 8] = pk;
    }
  } else if (m == 1) {               // Vc : (B,C,N)
#pragma unroll
    for (int i = 0; i < 8; ++i) {
      int o = ty * 8 + i;
      bf16x8 pk;
#pragma unroll
      for (int j = 0; j < 8; ++j) pk[j] = (__bf16)acc[i][j];
      *(bf16x8*)&Vc[((size_t)(b * 64 + o)) * 4096 + n0 + tx * 8] = pk;
    }
  } else {                           // q branch: 2x2 avg pool -> qt (B,P,C)
    float pl[8][4];
#pragma unroll
    for (int i = 0; i < 8; ++i)
#pragma unroll
      for (int jj = 0; jj < 4; ++jj)
        pl[i][jj] = acc[i][2 * jj] + acc[i][2 * jj + 1];
#pragma unroll
    for (int i = 0; i < 8; ++i)
#pragma unroll
      for (int jj = 0; jj < 4; ++jj)
        pl[i][jj] += __shfl_xor(pl[i][jj], 8);
    if (tx < 8) {
#pragma unroll
      for (int jj = 0; jj < 4; ++jj) {
        int p = rp * 32 + tx * 4 + jj;
        bf16x8 pk;
#pragma unroll
        for (int i = 0; i < 8; ++i) pk[i] = (__bf16)(0.25f * pl[i][jj]);
        *(bf16x8*)&qt[((size_t)(b * 1024 + p)) * 64 + ty * 8] = pk;
      }
    }
  }
}

// ---------------------------------------------------------------------------
// Stage 1, flash-decoding: grid 512 = b8 x qb8 x ks8. 8 waves each own one
// q-tile (128 q/block); kv span 512, 8 rounds of 64. Raw (acc,m,l) partials.
// LDS: K 2x8K @0 | V 2x8K @16384 | P 8x2K @32768 = 48 KB -> 2 blocks/CU.
// ---------------------------------------------------------------------------
__global__ __launch_bounds__(512, 4) void attn1_kernel(
    const __bf16* __restrict__ Qg,   // qt (B,1024,64)
    const __bf16* __restrict__ Kg,   // Kt (B,4096,64)
    const __bf16* __restrict__ Vg,   // Vc (B,64,4096)
    float* __restrict__ partO,       // [b][qb][ks][c64][q128]
    float2* __restrict__ partML)     // [b][qb][ks][q128]
{
  __shared__ __align__(16) char smem[49152];

  const int tid  = threadIdx.x;
  const int wave = tid >> 6, lane = tid & 63;
  const int lg = (lane >> 4) & 3, lp = lane & 15;
  const int b  = blockIdx.x >> 6;
  const int qb = (blockIdx.x >> 3) & 7;
  const int ks = blockIdx.x & 7;

  const int qw = wave * 16 + lp;
  const __bf16* qg = Qg + ((size_t)(b * 1024 + qb * 128 + qw)) * 64;
  const bf16x8 qf0 = *(const bf16x8*)(qg + lg * 8);
  const bf16x8 qf1 = *(const bf16x8*)(qg + 32 + lg * 8);

  f32x4 acc[4];
#pragma unroll
  for (int ct = 0; ct < 4; ++ct) acc[ct] = (f32x4){0.f, 0.f, 0.f, 0.f};
  float m_run = -3.0e38f, l_run = 0.0f;

  bf16x8 kreg, vreg;
  const int sw = swz(tid & 511);
  auto load_tile = [&](int r) {
    int kv0 = ks * 512 + r * 64;
    kreg = *(const bf16x8*)(Kg + ((size_t)(b * 4096 + kv0 + (tid >> 3))) * 64 + (tid & 7) * 8);
    vreg = *(const bf16x8*)(Vg + ((size_t)(b * 64 + (tid >> 3))) * 4096 + kv0 + (tid & 7) * 8);
  };
  auto write_tile = [&](int nb) {
    *(bf16x8*)((__bf16*)(smem + nb * 8192) + sw * 8) = kreg;
    *(bf16x8*)((__bf16*)(smem + 16384 + nb * 8192) + sw * 8) = vreg;
  };

  load_tile(0); write_tile(0);
  load_tile(1);
  __syncthreads();

  for (int r = 0; r < 8; ++r) {
    const int cur = r & 1;
    if (r + 1 < 8) write_tile(cur ^ 1);
    if (r + 2 < 8) load_tile(r + 2);

    const __bf16* lK = (const __bf16*)(smem + cur * 8192);
    const __bf16* lV = (const __bf16*)(smem + 16384 + cur * 8192);
    __bf16* lP = (__bf16*)(smem + 32768) + wave * 1024;

    f32x4 S[4];
#pragma unroll
    for (int mt = 0; mt < 4; ++mt) {
      int ch0 = (mt * 16 + lp) * 8 + lg;
      bf16x8 a0 = *(const bf16x8*)(lK + swz(ch0) * 8);
      bf16x8 a1 = *(const bf16x8*)(lK + swz(ch0 + 4) * 8);
      f32x4 z = (f32x4){0.f, 0.f, 0.f, 0.f};
      z = __builtin_amdgcn_mfma_f32_16x16x32_bf16(a0, qf0, z, 0, 0, 0);
      z = __builtin_amdgcn_mfma_f32_16x16x32_bf16(a1, qf1, z, 0, 0, 0);
      S[mt] = z;
    }

    float tmax = -3.0e38f;
#pragma unroll
    for (int mt = 0; mt < 4; ++mt)
#pragma unroll
      for (int rr = 0; rr < 4; ++rr) tmax = fmaxf(tmax, S[mt][rr]);
    tmax = fmaxf(tmax, __shfl_xor(tmax, 16));
    tmax = fmaxf(tmax, __shfl_xor(tmax, 32));
    float mnew = fmaxf(m_run, tmax);
    float sc = __expf(m_run - mnew);
    float rs = 0.f;
#pragma unroll
    for (int mt = 0; mt < 4; ++mt)
#pragma unroll
      for (int rr = 0; rr < 4; ++rr) {
        float e = __expf(S[mt][rr] - mnew);
        S[mt][rr] = e;
        rs += e;
      }
    rs += __shfl_xor(rs, 16);
    rs += __shfl_xor(rs, 32);
    l_run = l_run * sc + rs;
    m_run = mnew;
#pragma unroll
    for (int ct = 0; ct < 4; ++ct) acc[ct] *= sc;

#pragma unroll
    for (int mt = 0; mt < 4; ++mt) {
      bf16x4 pk;
#pragma unroll
      for (int rr = 0; rr < 4; ++rr) pk[rr] = (__bf16)S[mt][rr];
      int boff = lp * 128 + mt * 32 + lg * 8;
      *(bf16x4*)((char*)lP + (boff ^ ((lp & 7) << 4))) = pk;
    }

    {
      int chp = lp * 8 + lg;
      bf16x8 pf0 = *(const bf16x8*)(lP + swz(chp) * 8);
      bf16x8 pf1 = *(const bf16x8*)(lP + swz(chp + 4) * 8);
#pragma unroll
      for (int ct = 0; ct < 4; ++ct) {
        int chv = (ct * 16 + lp) * 8 + lg;
        bf16x8 v0 = *(const bf16x8*)(lV + swz(chv) * 8);
        bf16x8 v1 = *(const bf16x8*)(lV + swz(chv + 4) * 8);
        acc[ct] = __builtin_amdgcn_mfma_f32_16x16x32_bf16(v0, pf0, acc[ct], 0, 0, 0);
        acc[ct] = __builtin_amdgcn_mfma_f32_16x16x32_bf16(v1, pf1, acc[ct], 0, 0, 0);
      }
    }
    __syncthreads();
  }

  // raw partials (no normalization here)
  const size_t pbase = ((size_t)(b * 8 + qb)) * 8 + ks;
  if (lg == 0) partML[pbase * 128 + qw] = make_float2(m_run, l_run);
  float* po = partO + pbase * 64 * 128;
#pragma unroll
  for (int ct = 0; ct < 4; ++ct)
#pragma unroll
    for (int rr = 0; rr < 4; ++rr)
      po[(ct * 16 + lg * 4 + rr) * 128 + qw] = acc[ct][rr];
}

// ---------------------------------------------------------------------------
// Combine 8 kv-splits -> O1 bf16. Grid 256 = b8 x qb8 x cq4; 256 thr.
// ---------------------------------------------------------------------------
__global__ __launch_bounds__(256) void combine1_kernel(
    const float* __restrict__ partO, const float2* __restrict__ partML,
    __bf16* __restrict__ O1)
{
  __shared__ float fs[8][128];
  __shared__ float inv[128];

  const int tid = threadIdx.x;
  const int b   = blockIdx.x >> 5;
  const int qb  = (blockIdx.x >> 2) & 7;
  const int c0  = (blockIdx.x & 3) * 16;
  const size_t mbase = ((size_t)(b * 8 + qb)) * 8;

  if (tid < 128) {
    float mm[8], lv[8];
    float mstar = -3.0e38f;
#pragma unroll
    for (int s = 0; s < 8; ++s) {
      float2 v = partML[(mbase + s) * 128 + tid];
      mm[s] = v.x; lv[s] = v.y;
      mstar = fmaxf(mstar, mm[s]);
    }
    float l = 0.f;
#pragma unroll
    for (int s = 0; s < 8; ++s) {
      float fv = __expf(mm[s] - mstar);
      fs[s][tid] = fv;
      l += lv[s] * fv;
    }
    inv[tid] = 1.0f / l;
  }
  __syncthreads();

  for (int i = tid; i < 2048; i += 256) {
    int cl = i >> 7, q = i & 127, c = c0 + cl;
    float o = 0.f;
#pragma unroll
    for (int s = 0; s < 8; ++s)
      o += fs[s][q] * partO[((mbase + s) * 64 + c) * 128 + q];
    O1[((size_t)(b * 64 + c)) * 1024 + qb * 128 + q] = (__bf16)(o * inv[q]);
  }
}

// ---------------------------------------------------------------------------
// Stage 2: grid 512 = b8 x qb64 (64 q/block). 8 waves = 4 q-tiles x 2
// kv-halves (512 anchors each), 8 rounds of 64. In-block LDS combine +
// fused epilogue. LDS: K 2sp x 2buf x 8K @0 | V same @32768 | P @65536 = 80K
// -> exactly 2 blocks/CU = 16 waves/CU.
// ---------------------------------------------------------------------------
__global__ __launch_bounds__(512, 4) void attn2_kernel(
    const __bf16* __restrict__ Qg,   // Qt (B,4096,64)
    const __bf16* __restrict__ Kg,   // qt (B,1024,64)
    const __bf16* __restrict__ Vg,   // O1 (B,64,1024)
    float* __restrict__ outp,        // (B,64,4096) f32
    const float* __restrict__ xres,
    const float* __restrict__ gammap)
{
  __shared__ __align__(16) char smem[81920];

  const int tid  = threadIdx.x;
  const int wave = tid >> 6, lane = tid & 63;
  const int lg = (lane >> 4) & 3, lp = lane & 15;
  const int qt4 = wave & 3, ks = wave >> 2;
  const int b  = blockIdx.x >> 6;
  const int q0 = (blockIdx.x & 63) * 64;
  const int myq = q0 + qt4 * 16 + lp;

  const __bf16* qg = Qg + ((size_t)(b * 4096 + myq)) * 64;
  const bf16x8 qf0 = *(const bf16x8*)(qg + lg * 8);
  const bf16x8 qf1 = *(const bf16x8*)(qg + 32 + lg * 8);

  f32x4 acc[4];
#pragma unroll
  for (int ct = 0; ct < 4; ++ct) acc[ct] = (f32x4){0.f, 0.f, 0.f, 0.f};
  float m_run = -3.0e38f, l_run = 0.0f;

  bf16x8 kreg[2], vreg[2];
  const int cs = tid & 255;   // chunk base within this thread's staged split
  const int sp = tid >> 8;    // split this thread stages
  const int sw0 = swz(cs), sw1 = swz(cs + 256);
  auto load_tile = [&](int r) {
    int a0 = sp * 512 + r * 64;
#pragma unroll
    for (int j = 0; j < 2; ++j) {
      int s = cs + j * 256;
      int row = s >> 3, col = (s & 7) * 8;
      kreg[j] = *(const bf16x8*)(Kg + ((size_t)(b * 1024 + a0 + row)) * 64 + col);
      vreg[j] = *(const bf16x8*)(Vg + ((size_t)(b * 64 + row)) * 1024 + a0 + col);
    }
  };
  auto write_tile = [&](int nb) {
    __bf16* kd = (__bf16*)(smem + (sp * 2 + nb) * 8192);
    __bf16* vd = (__bf16*)(smem + 32768 + (sp * 2 + nb) * 8192);
    *(bf16x8*)(kd + sw0 * 8) = kreg[0];
    *(bf16x8*)(kd + sw1 * 8) = kreg[1];
    *(bf16x8*)(vd + sw0 * 8) = vreg[0];
    *(bf16x8*)(vd + sw1 * 8) = vreg[1];
  };

  load_tile(0); write_tile(0);
  load_tile(1);
  __syncthreads();

  for (int r = 0; r < 8; ++r) {
    const int cur = r & 1;
    if (r + 1 < 8) write_tile(cur ^ 1);
    if (r + 2 < 8) load_tile(r + 2);

    const __bf16* lK = (const __bf16*)(smem + (ks * 2 + cur) * 8192);
    const __bf16* lV = (const __bf16*)(smem + 32768 + (ks * 2 + cur) * 8192);
    __bf16* lP = (__bf16*)(smem + 65536) + wave * 1024;

    f32x4 S[4];
#pragma unroll
    for (int mt = 0; mt < 4; ++mt) {
      int ch0 = (mt * 16 + lp) * 8 + lg;
      bf16x8 a0 = *(const bf16x8*)(lK + swz(ch0) * 8);
      bf16x8 a1 = *(const bf16x8*)(lK + swz(ch0 + 4) * 8);
      f32x4 z = (f32x4){0.f, 0.f, 0.f, 0.f};
      z = __builtin_amdgcn_mfma_f32_16x16x32_bf16(a0, qf0, z, 0, 0, 0);
      z = __builtin_amdgcn_mfma_f32_16x16x32_bf16(a1, qf1, z, 0, 0, 0);
      S[mt] = z;
    }

    float tmax = -3.0e38f;
#pragma unroll
    for (int mt = 0; mt < 4; ++mt)
#pragma unroll
      for (int rr = 0; rr < 4; ++rr) tmax = fmaxf(tmax, S[mt][rr]);
    tmax = fmaxf(tmax, __shfl_xor(tmax, 16));
    tmax = fmaxf(tmax, __shfl_xor(tmax, 32));
    float mnew = fmaxf(m_run, tmax);
    float sc = __expf(m_run - mnew);
    float rs = 0.f;
#pragma unroll
    for (int mt = 0; mt < 4; ++mt)
#pragma unroll
      for (int rr = 0; rr < 4; ++rr) {
        float e = __expf(S[mt][rr] - mnew);
        S[mt][rr] = e;
        rs += e;
      }
    rs += __shfl_xor(rs, 16);
    rs += __shfl_xor(rs, 32);
    l_run = l_run * sc + rs;
    m_run = mnew;
#pragma unroll
    for (int ct = 0; ct < 4; ++ct) acc[ct] *= sc;

#pragma unroll
    for (int mt = 0; mt < 4; ++mt) {
      bf16x4 pk;
#pragma unroll
      for (int rr = 0; rr < 4; ++rr) pk[rr] = (__bf16)S[mt][rr];
      int boff = lp * 128 + mt * 32 + lg * 8;
      *(bf16x4*)((char*)lP + (boff ^ ((lp & 7) << 4))) = pk;
    }

    {
      int chp = lp * 8 + lg;
      bf16x8 pf0 = *(const bf16x8*)(lP + swz(chp) * 8);
      bf16x8 pf1 = *(const bf16x8*)(lP + swz(chp + 4) * 8);
#pragma unroll
      for (int ct = 0; ct < 4; ++ct) {
        int chv = (ct * 16 + lp) * 8 + lg;
        bf16x8 v0 = *(const bf16x8*)(lV + swz(chv) * 8);
        bf16x8 v1 = *(const bf16x8*)(lV + swz(chv + 4) * 8);
        acc[ct] = __builtin_amdgcn_mfma_f32_16x16x32_bf16(v0, pf0, acc[ct], 0, 0, 0);
        acc[ct] = __builtin_amdgcn_mfma_f32_16x16x32_bf16(v1, pf1, acc[ct], 0, 0, 0);
      }
    }
    __syncthreads();
  }

  // ---- in-block 2-split combine (K region + P region are dead; reuse) ----
  float2* mlb = (float2*)(smem + 65536);
  if (lg == 0) mlb[wave * 16 + lp] = make_float2(m_run, l_run);
  float* cb = (float*)smem;  // [qt4][ks][p16][c64] f32 = 32 KB
  {
    float* myc = cb + ((size_t)((qt4 * 2 + ks) * 16 + lp)) * 64;
#pragma unroll
    for (int ct = 0; ct < 4; ++ct)
      *(f32x4*)(myc + ct * 16 + lg * 4) = acc[ct];
  }
  __syncthreads();

  if (wave < 4) {
    const int qtt = wave;
    const int nq = q0 + qtt * 16 + lp;
    float2 v0 = mlb[qtt * 16 + lp];        // ks = 0
    float2 v1 = mlb[(qtt + 4) * 16 + lp];  // ks = 1
    float mstar = fmaxf(v0.x, v1.x);
    float f0 = __expf(v0.x - mstar), f1 = __expf(v1.x - mstar);
    float inv = 1.0f / (v0.y * f0 + v1.y * f1);
    float g0 = gammap[0];
#pragma unroll
    for (int ct = 0; ct < 4; ++ct) {
      f32x4 t0 = *(const f32x4*)(cb + ((size_t)((qtt * 2 + 0) * 16 + lp)) * 64 +
                                 ct * 16 + lg * 4);
      f32x4 t1 = *(const f32x4*)(cb + ((size_t)((qtt * 2 + 1) * 16 + lp)) * 64 +
                                 ct * 16 + lg * 4);
      f32x4 o = f0 * t0 + f1 * t1;
#pragma unroll
      for (int rr = 0; rr < 4; ++rr) {
        int c = ct * 16 + lg * 4 + rr;
        size_t oi = ((size_t)(b * 64 + c)) * 4096 + nq;
        outp[oi] = g0 * (o[rr] * inv) + xres[oi];
      }
    }
  }
}

// ---------------------------------------------------------------------------
extern "C" void kernel_launch(void* const* d_in, const int* in_sizes, int n_in,
                              void* d_out, int out_size, void* d_ws, size_t ws_size,
                              hipStream_t stream) {
  const float* x     = (const float*)d_in[0];
  const float* wq    = (const float*)d_in[1];
  const float* bq    = (const float*)d_in[2];
  const float* wQ    = (const float*)d_in[3];
  const float* bQ    = (const float*)d_in[4];
  const float* wK    = (const float*)d_in[5];
  const float* bK    = (const float*)d_in[6];
  const float* wV    = (const float*)d_in[7];
  const float* bV    = (const float*)d_in[8];
  const float* gamma = (const float*)d_in[9];

  __bf16* ws = (__bf16*)d_ws;
  __bf16* Kt = ws;
  __bf16* Vc = ws + 2097152;
  __bf16* Qt = ws + 4194304;
  __bf16* qt = ws + 6291456;
  __bf16* O1 = ws + 6815744;
  float*  partO  = (float*)((char*)d_ws + (16u << 20));
  float2* partML = (float2*)((char*)d_ws + (32u << 20));

  hipLaunchKernelGGL(conv4_kernel, dim3(1024), dim3(128), 0, stream,
                     x, wq, bq, wQ, bQ, wK, bK, wV, bV, Kt, Vc, Qt, qt);
  hipLaunchKernelGGL(attn1_kernel, dim3(512), dim3(512), 0, stream,
                     qt, Kt, Vc, partO, partML);
  hipLaunchKernelGGL(combine1_kernel, dim3(256), dim3(256), 0, stream,
                     partO, partML, O1);
  hipLaunchKernelGGL(attn2_kernel, dim3(512), dim3(512), 0, stream,
                     Qt, qt, O1, (float*)d_out, x, gamma);
}

// Round 5
// 74.087 us; speedup vs baseline: 1.0941x; 1.0941x over previous
//
#include <hip/hip_runtime.h>
#include <hip/hip_bf16.h>

// Problem: B=8, C=64, H=W=64, N=4096, P=1024.
// ws layout:
//   bf16 region (elements):
//     Kt (B,N,C) @ 0          Vc (B,C,N) @ 2097152
//     Qt (B,N,C) @ 4194304    qt (B,P,C) @ 6291456
//     O1 (B,C,P) @ 6815744    (ends at 14.7 MB)
//   byte 16 MB: partO  f32 [b8][qb4][ks8][c64][q256]  (16 MB)
//   byte 32 MB: partML f32x2 [b8][qb4][ks8][q256]     (0.5 MB)

typedef float  f32x4  __attribute__((ext_vector_type(4)));
typedef __bf16 bf16x8 __attribute__((ext_vector_type(8)));
typedef __bf16 bf16x4 __attribute__((ext_vector_type(4)));

// chunk (16B) XOR swizzle within each 64-chunk (8-row) group
__device__ __forceinline__ int swz(int ch) { return ch ^ ((ch >> 3) & 7); }

// ---------------------------------------------------------------------------
// Kernel 1: four 1x1 convs (+bias), fp32, bf16 outputs in MFMA layouts.
// (round-2 verified version, unchanged)
// ---------------------------------------------------------------------------
__global__ __launch_bounds__(256) void conv4_kernel(
    const float* __restrict__ x,
    const float* __restrict__ wq, const float* __restrict__ bq,
    const float* __restrict__ wQ, const float* __restrict__ bQ,
    const float* __restrict__ wK, const float* __restrict__ bK,
    const float* __restrict__ wV, const float* __restrict__ bV,
    __bf16* __restrict__ Kt, __bf16* __restrict__ Vc,
    __bf16* __restrict__ Qt, __bf16* __restrict__ qt)
{
  __shared__ float xs[64 * 132];
  __shared__ float wsh[64 * 68];

  const int tid = threadIdx.x;
  const int m   = blockIdx.x >> 8;
  const int b   = (blockIdx.x >> 5) & 7;
  const int rp  = blockIdx.x & 31;
  const int n0  = rp << 7;

  const float* wg = (m == 0) ? wK : (m == 1) ? wV : (m == 2) ? wQ : wq;
  const float* bg = (m == 0) ? bK : (m == 1) ? bV : (m == 2) ? bQ : bq;

  for (int i = tid; i < 64 * 32; i += 256) {
    int c = i >> 5, j = i & 31;
    *(f32x4*)&xs[c * 132 + j * 4] =
        *(const f32x4*)&x[((size_t)(b * 64 + c)) * 4096 + n0 + j * 4];
  }
  for (int i = tid; i < 1024; i += 256) {
    int o = i >> 4, c0 = (i & 15) << 2;
    f32x4 v = *(const f32x4*)&wg[o * 64 + c0];
    wsh[(c0 + 0) * 68 + o] = v[0];
    wsh[(c0 + 1) * 68 + o] = v[1];
    wsh[(c0 + 2) * 68 + o] = v[2];
    wsh[(c0 + 3) * 68 + o] = v[3];
  }
  __syncthreads();

  const int ty = tid >> 4, tx = tid & 15;

  float acc[4][8];
  {
    f32x4 bv = *(const f32x4*)&bg[ty * 4];
#pragma unroll
    for (int i = 0; i < 4; ++i)
#pragma unroll
      for (int j = 0; j < 8; ++j) acc[i][j] = bv[i];
  }

#pragma unroll 4
  for (int c = 0; c < 64; ++c) {
    f32x4 wv = *(const f32x4*)&wsh[c * 68 + ty * 4];
    f32x4 xa = *(const f32x4*)&xs[c * 132 + tx * 8];
    f32x4 xb = *(const f32x4*)&xs[c * 132 + tx * 8 + 4];
#pragma unroll
    for (int i = 0; i < 4; ++i) {
#pragma unroll
      for (int j = 0; j < 4; ++j) {
        acc[i][j]     += wv[i] * xa[j];
        acc[i][j + 4] += wv[i] * xb[j];
      }
    }
  }

  if (m == 0 || m == 2) {            // Kt / Qt : (B,N,C)
    __bf16* dst = (m == 0) ? Kt : Qt;
#pragma unroll
    for (int j = 0; j < 8; ++j) {
      int n = n0 + tx * 8 + j;
      bf16x4 pk;
#pragma unroll
      for (int i = 0; i < 4; ++i) pk[i] = (__bf16)acc[i][j];
      *(bf16x4*)&dst[((size_t)(b * 4096 + n)) * 64 + ty * 4] = pk;
    }
  } else if (m == 1) {               // Vc : (B,C,N)
#pragma unroll
    for (int i = 0; i < 4; ++i) {
      int o = ty * 4 + i;
      bf16x8 pk;
#pragma unroll
      for (int j = 0; j < 8; ++j) pk[j] = (__bf16)acc[i][j];
      *(bf16x8*)&Vc[((size_t)(b * 64 + o)) * 4096 + n0 + tx * 8] = pk;
    }
  } else {                           // q branch: 2x2 avg pool -> qt (B,P,C)
    float pl[4][4];
#pragma unroll
    for (int i = 0; i < 4; ++i)
#pragma unroll
      for (int jj = 0; jj < 4; ++jj)
        pl[i][jj] = acc[i][2 * jj] + acc[i][2 * jj + 1];
#pragma unroll
    for (int i = 0; i < 4; ++i)
#pragma unroll
      for (int jj = 0; jj < 4; ++jj)
        pl[i][jj] += __shfl_xor(pl[i][jj], 8);
    if (tx < 8) {
#pragma unroll
      for (int jj = 0; jj < 4; ++jj) {
        int p = rp * 32 + tx * 4 + jj;
        bf16x4 pk;
#pragma unroll
        for (int i = 0; i < 4; ++i) pk[i] = (__bf16)(0.25f * pl[i][jj]);
        *(bf16x4*)&qt[((size_t)(b * 1024 + p)) * 64 + ty * 4] = pk;
      }
    }
  }
}

// ---------------------------------------------------------------------------
// Stage 1 v2: 32 q/wave. Grid 256 = b8 x qb4 x ks8; 8 waves x 32 q = 256 q
// per block; ALL waves share one staged 64-kv K/V tile; 8 rounds of 64 kv.
// K fragments hoisted across the two q-sets (LDS reads amortized 2x).
// Raw (acc,m,l) partials to global. LDS: K 2x8K | V 2x8K | P 8x4K = 64 KB.
// ---------------------------------------------------------------------------
__global__ __launch_bounds__(512, 2) void attn1_kernel(
    const __bf16* __restrict__ Qg,   // qt (B,1024,64)
    const __bf16* __restrict__ Kg,   // Kt (B,4096,64)
    const __bf16* __restrict__ Vg,   // Vc (B,64,4096)
    float* __restrict__ partO,       // [b][qb][ks][c64][q256]
    float2* __restrict__ partML)     // [b][qb][ks][q256]
{
  __shared__ __align__(16) char smem[65536];

  const int tid = threadIdx.x;
  const int w = tid >> 6, lane = tid & 63;
  const int lg = (lane >> 4) & 3, lp = lane & 15;
  const int b  = blockIdx.x >> 5;
  const int qb = (blockIdx.x >> 3) & 3;
  const int ks = blockIdx.x & 7;

  bf16x8 qf[2][2];
#pragma unroll
  for (int qs = 0; qs < 2; ++qs) {
    const __bf16* qg =
        Qg + ((size_t)(b * 1024 + qb * 256 + w * 32 + qs * 16 + lp)) * 64;
    qf[qs][0] = *(const bf16x8*)(qg + lg * 8);
    qf[qs][1] = *(const bf16x8*)(qg + 32 + lg * 8);
  }

  f32x4 acc[2][4];
#pragma unroll
  for (int qs = 0; qs < 2; ++qs)
#pragma unroll
    for (int ct = 0; ct < 4; ++ct) acc[qs][ct] = (f32x4){0.f, 0.f, 0.f, 0.f};
  float m_run[2] = {-3.0e38f, -3.0e38f}, l_run[2] = {0.f, 0.f};

  bf16x8 kreg, vreg;
  const int swt = swz(tid);
  auto load_tile = [&](int r) {
    const int kv0 = ks * 512 + r * 64;
    kreg = *(const bf16x8*)(Kg + ((size_t)(b * 4096 + kv0 + (tid >> 3))) * 64 +
                            (tid & 7) * 8);
    vreg = *(const bf16x8*)(Vg + ((size_t)(b * 64 + (tid >> 3))) * 4096 + kv0 +
                            (tid & 7) * 8);
  };
  auto write_tile = [&](int nb) {
    *(bf16x8*)((__bf16*)(smem + nb * 8192) + swt * 8) = kreg;
    *(bf16x8*)((__bf16*)(smem + 16384 + nb * 8192) + swt * 8) = vreg;
  };

  load_tile(0); write_tile(0); load_tile(1);
  __syncthreads();

  for (int r = 0; r < 8; ++r) {
    const int cur = r & 1;
    if (r + 1 < 8) write_tile(cur ^ 1);
    if (r + 2 < 8) load_tile(r + 2);

    const __bf16* lK = (const __bf16*)(smem + cur * 8192);
    const __bf16* lV = (const __bf16*)(smem + 16384 + cur * 8192);
    __bf16* lP = (__bf16*)(smem + 32768) + w * 2048;

    bf16x8 ka[4][2];
#pragma unroll
    for (int mt = 0; mt < 4; ++mt) {
      int ch0 = (mt * 16 + lp) * 8 + lg;
      ka[mt][0] = *(const bf16x8*)(lK + swz(ch0) * 8);
      ka[mt][1] = *(const bf16x8*)(lK + swz(ch0 + 4) * 8);
    }

#pragma unroll
    for (int qs = 0; qs < 2; ++qs) {
      f32x4 S[4];
#pragma unroll
      for (int mt = 0; mt < 4; ++mt) {
        f32x4 z = (f32x4){0.f, 0.f, 0.f, 0.f};
        z = __builtin_amdgcn_mfma_f32_16x16x32_bf16(ka[mt][0], qf[qs][0], z, 0, 0, 0);
        z = __builtin_amdgcn_mfma_f32_16x16x32_bf16(ka[mt][1], qf[qs][1], z, 0, 0, 0);
        S[mt] = z;
      }

      float tmax = -3.0e38f;
#pragma unroll
      for (int mt = 0; mt < 4; ++mt)
#pragma unroll
        for (int rr = 0; rr < 4; ++rr) tmax = fmaxf(tmax, S[mt][rr]);
      tmax = fmaxf(tmax, __shfl_xor(tmax, 16));
      tmax = fmaxf(tmax, __shfl_xor(tmax, 32));
      float mnew = fmaxf(m_run[qs], tmax);
      float sc = __expf(m_run[qs] - mnew);
      float rs = 0.f;
#pragma unroll
      for (int mt = 0; mt < 4; ++mt)
#pragma unroll
        for (int rr = 0; rr < 4; ++rr) {
          float e = __expf(S[mt][rr] - mnew);
          S[mt][rr] = e;
          rs += e;
        }
      rs += __shfl_xor(rs, 16);
      rs += __shfl_xor(rs, 32);
      l_run[qs] = l_run[qs] * sc + rs;
      m_run[qs] = mnew;
#pragma unroll
      for (int ct = 0; ct < 4; ++ct) acc[qs][ct] *= sc;

#pragma unroll
      for (int mt = 0; mt < 4; ++mt) {
        bf16x4 pk;
#pragma unroll
        for (int rr = 0; rr < 4; ++rr) pk[rr] = (__bf16)S[mt][rr];
        int boff = (qs * 16 + lp) * 128 + mt * 32 + lg * 8;
        *(bf16x4*)((char*)lP + (boff ^ ((lp & 7) << 4))) = pk;
      }
    }

    bf16x8 pf[2][2];
#pragma unroll
    for (int qs = 0; qs < 2; ++qs) {
      int chp = (qs * 16 + lp) * 8 + lg;
      pf[qs][0] = *(const bf16x8*)(lP + swz(chp) * 8);
      pf[qs][1] = *(const bf16x8*)(lP + swz(chp + 4) * 8);
    }
#pragma unroll
    for (int ct = 0; ct < 4; ++ct) {
      int chv = (ct * 16 + lp) * 8 + lg;
      bf16x8 v0 = *(const bf16x8*)(lV + swz(chv) * 8);
      bf16x8 v1 = *(const bf16x8*)(lV + swz(chv + 4) * 8);
#pragma unroll
      for (int qs = 0; qs < 2; ++qs) {
        acc[qs][ct] = __builtin_amdgcn_mfma_f32_16x16x32_bf16(v0, pf[qs][0], acc[qs][ct], 0, 0, 0);
        acc[qs][ct] = __builtin_amdgcn_mfma_f32_16x16x32_bf16(v1, pf[qs][1], acc[qs][ct], 0, 0, 0);
      }
    }
    __syncthreads();
  }

  const size_t pbase = (size_t)((b * 4 + qb) * 8 + ks);
  if (lg == 0) {
#pragma unroll
    for (int qs = 0; qs < 2; ++qs)
      partML[pbase * 256 + w * 32 + qs * 16 + lp] =
          make_float2(m_run[qs], l_run[qs]);
  }
  float* po = partO + pbase * 16384;
#pragma unroll
  for (int qs = 0; qs < 2; ++qs)
#pragma unroll
    for (int ct = 0; ct < 4; ++ct)
#pragma unroll
      for (int rr = 0; rr < 4; ++rr)
        po[(ct * 16 + lg * 4 + rr) * 256 + w * 32 + qs * 16 + lp] =
            acc[qs][ct][rr];
}

// ---------------------------------------------------------------------------
// Combine 8 kv-splits -> O1 bf16. Grid 256 = b8 x qb4 x cs8; 256 thr.
// ---------------------------------------------------------------------------
__global__ __launch_bounds__(256) void combine1_kernel(
    const float* __restrict__ partO, const float2* __restrict__ partML,
    __bf16* __restrict__ O1)
{
  __shared__ float fs[8][256];
  __shared__ float inv[256];

  const int tid = threadIdx.x;
  const int b   = blockIdx.x >> 5;
  const int qb  = (blockIdx.x >> 3) & 3;
  const int cs  = blockIdx.x & 7;
  const size_t mbase = (size_t)(b * 4 + qb) * 8;

  {
    float mm[8], lv[8];
    float mstar = -3.0e38f;
#pragma unroll
    for (int s = 0; s < 8; ++s) {
      float2 v = partML[(mbase + s) * 256 + tid];
      mm[s] = v.x; lv[s] = v.y;
      mstar = fmaxf(mstar, mm[s]);
    }
    float l = 0.f;
#pragma unroll
    for (int s = 0; s < 8; ++s) {
      float fv = __expf(mm[s] - mstar);
      fs[s][tid] = fv;
      l += lv[s] * fv;
    }
    inv[tid] = 1.0f / l;
  }
  __syncthreads();

  for (int i = tid; i < 2048; i += 256) {
    int c = cs * 8 + (i >> 8), q = i & 255;
    float o = 0.f;
#pragma unroll
    for (int s = 0; s < 8; ++s)
      o += fs[s][q] * partO[((mbase + s) * 64 + c) * 256 + q];
    O1[((size_t)(b * 64 + c)) * 1024 + qb * 256 + q] = (__bf16)(o * inv[q]);
  }
}

// ---------------------------------------------------------------------------
// Stage 2 v4: 32 q/wave. Grid 256 = b8 x qb32; 8 waves = 4 qg x 2 ks halves
// (512 anchors each), 128 q/block, 8 rounds of 64. In-block LDS combine
// (cb rows padded to 68 f32; mlb sized 8x32 float2 AFTER cb — R4 bug was a
// 512-B mlb at the end of smem overflowing the allocation) + fused epilogue.
// LDS: K 2ks x 2buf x 8K @0 | V same @32768 | P 8x4K @65536 = 96 KB.
// ---------------------------------------------------------------------------
__global__ __launch_bounds__(512, 2) void attn2_kernel(
    const __bf16* __restrict__ Qg,   // Qt (B,4096,64)
    const __bf16* __restrict__ Kg,   // qt (B,1024,64)
    const __bf16* __restrict__ Vg,   // O1 (B,64,1024)
    float* __restrict__ outp,        // (B,64,4096) f32
    const float* __restrict__ xres,
    const float* __restrict__ gammap)
{
  __shared__ __align__(16) char smem[98304];

  const int tid = threadIdx.x;
  const int w = tid >> 6, lane = tid & 63;
  const int lg = (lane >> 4) & 3, lp = lane & 15;
  const int qg4 = w & 3, ks = w >> 2;
  const int b  = blockIdx.x >> 5;
  const int q0 = (blockIdx.x & 31) * 128;

  bf16x8 qf[2][2];
#pragma unroll
  for (int qs = 0; qs < 2; ++qs) {
    const __bf16* qg =
        Qg + ((size_t)(b * 4096 + q0 + qg4 * 32 + qs * 16 + lp)) * 64;
    qf[qs][0] = *(const bf16x8*)(qg + lg * 8);
    qf[qs][1] = *(const bf16x8*)(qg + 32 + lg * 8);
  }

  f32x4 acc[2][4];
#pragma unroll
  for (int qs = 0; qs < 2; ++qs)
#pragma unroll
    for (int ct = 0; ct < 4; ++ct) acc[qs][ct] = (f32x4){0.f, 0.f, 0.f, 0.f};
  float m_run[2] = {-3.0e38f, -3.0e38f}, l_run[2] = {0.f, 0.f};

  bf16x8 kreg[2], vreg[2];
  const int csi = tid & 255, sp = tid >> 8;
  const int sw0 = swz(csi), sw1 = swz(csi + 256);
  auto load_tile = [&](int r) {
    const int a0 = sp * 512 + r * 64;
#pragma unroll
    for (int j = 0; j < 2; ++j) {
      int s = csi + j * 256;
      int row = s >> 3, col = (s & 7) * 8;
      kreg[j] = *(const bf16x8*)(Kg + ((size_t)(b * 1024 + a0 + row)) * 64 + col);
      vreg[j] = *(const bf16x8*)(Vg + ((size_t)(b * 64 + row)) * 1024 + a0 + col);
    }
  };
  auto write_tile = [&](int nb) {
    __bf16* kd = (__bf16*)(smem + (sp * 2 + nb) * 8192);
    __bf16* vd = (__bf16*)(smem + 32768 + (sp * 2 + nb) * 8192);
    *(bf16x8*)(kd + sw0 * 8) = kreg[0];
    *(bf16x8*)(kd + sw1 * 8) = kreg[1];
    *(bf16x8*)(vd + sw0 * 8) = vreg[0];
    *(bf16x8*)(vd + sw1 * 8) = vreg[1];
  };

  load_tile(0); write_tile(0); load_tile(1);
  __syncthreads();

  for (int r = 0; r < 8; ++r) {
    const int cur = r & 1;
    if (r + 1 < 8) write_tile(cur ^ 1);
    if (r + 2 < 8) load_tile(r + 2);

    const __bf16* lK = (const __bf16*)(smem + (ks * 2 + cur) * 8192);
    const __bf16* lV = (const __bf16*)(smem + 32768 + (ks * 2 + cur) * 8192);
    __bf16* lP = (__bf16*)(smem + 65536) + w * 2048;

    bf16x8 ka[4][2];
#pragma unroll
    for (int mt = 0; mt < 4; ++mt) {
      int ch0 = (mt * 16 + lp) * 8 + lg;
      ka[mt][0] = *(const bf16x8*)(lK + swz(ch0) * 8);
      ka[mt][1] = *(const bf16x8*)(lK + swz(ch0 + 4) * 8);
    }

#pragma unroll
    for (int qs = 0; qs < 2; ++qs) {
      f32x4 S[4];
#pragma unroll
      for (int mt = 0; mt < 4; ++mt) {
        f32x4 z = (f32x4){0.f, 0.f, 0.f, 0.f};
        z = __builtin_amdgcn_mfma_f32_16x16x32_bf16(ka[mt][0], qf[qs][0], z, 0, 0, 0);
        z = __builtin_amdgcn_mfma_f32_16x16x32_bf16(ka[mt][1], qf[qs][1], z, 0, 0, 0);
        S[mt] = z;
      }

      float tmax = -3.0e38f;
#pragma unroll
      for (int mt = 0; mt < 4; ++mt)
#pragma unroll
        for (int rr = 0; rr < 4; ++rr) tmax = fmaxf(tmax, S[mt][rr]);
      tmax = fmaxf(tmax, __shfl_xor(tmax, 16));
      tmax = fmaxf(tmax, __shfl_xor(tmax, 32));
      float mnew = fmaxf(m_run[qs], tmax);
      float sc = __expf(m_run[qs] - mnew);
      float rs = 0.f;
#pragma unroll
      for (int mt = 0; mt < 4; ++mt)
#pragma unroll
        for (int rr = 0; rr < 4; ++rr) {
          float e = __expf(S[mt][rr] - mnew);
          S[mt][rr] = e;
          rs += e;
        }
      rs += __shfl_xor(rs, 16);
      rs += __shfl_xor(rs, 32);
      l_run[qs] = l_run[qs] * sc + rs;
      m_run[qs] = mnew;
#pragma unroll
      for (int ct = 0; ct < 4; ++ct) acc[qs][ct] *= sc;

#pragma unroll
      for (int mt = 0; mt < 4; ++mt) {
        bf16x4 pk;
#pragma unroll
        for (int rr = 0; rr < 4; ++rr) pk[rr] = (__bf16)S[mt][rr];
        int boff = (qs * 16 + lp) * 128 + mt * 32 + lg * 8;
        *(bf16x4*)((char*)lP + (boff ^ ((lp & 7) << 4))) = pk;
      }
    }

    bf16x8 pf[2][2];
#pragma unroll
    for (int qs = 0; qs < 2; ++qs) {
      int chp = (qs * 16 + lp) * 8 + lg;
      pf[qs][0] = *(const bf16x8*)(lP + swz(chp) * 8);
      pf[qs][1] = *(const bf16x8*)(lP + swz(chp + 4) * 8);
    }
#pragma unroll
    for (int ct = 0; ct < 4; ++ct) {
      int chv = (ct * 16 + lp) * 8 + lg;
      bf16x8 v0 = *(const bf16x8*)(lV + swz(chv) * 8);
      bf16x8 v1 = *(const bf16x8*)(lV + swz(chv + 4) * 8);
#pragma unroll
      for (int qs = 0; qs < 2; ++qs) {
        acc[qs][ct] = __builtin_amdgcn_mfma_f32_16x16x32_bf16(v0, pf[qs][0], acc[qs][ct], 0, 0, 0);
        acc[qs][ct] = __builtin_amdgcn_mfma_f32_16x16x32_bf16(v1, pf[qs][1], acc[qs][ct], 0, 0, 0);
      }
    }
    __syncthreads();
  }

  // ---- in-block 2-split combine ----
  // cb: [wave][q32][68] f32 = 69,632 B @ 0 (overlays dead K/V regions).
  // mlb: 8 waves x 32 q float2 = 2,048 B @ 69,632 (FIX: was 512 B at end of
  // smem in R4 -> out-of-bounds -> inf).
  float*  cb  = (float*)smem;
  float2* mlb = (float2*)(smem + 69632);
  if (lg == 0) {
#pragma unroll
    for (int qs = 0; qs < 2; ++qs)
      mlb[w * 32 + qs * 16 + lp] = make_float2(m_run[qs], l_run[qs]);
  }
  {
    float* myc = cb + w * 2176;
#pragma unroll
    for (int qs = 0; qs < 2; ++qs)
#pragma unroll
      for (int ct = 0; ct < 4; ++ct)
        *(f32x4*)(myc + (qs * 16 + lp) * 68 + ct * 16 + lg * 4) = acc[qs][ct];
  }
  __syncthreads();

  if (w < 4) {
    const int g = w;
    const float g0 = gammap[0];
#pragma unroll
    for (int qs = 0; qs < 2; ++qs) {
      const int qq = qs * 16 + lp;
      const int nq = q0 + g * 32 + qq;
      float2 v0 = mlb[g * 32 + qq];
      float2 v1 = mlb[(g + 4) * 32 + qq];
      float mstar = fmaxf(v0.x, v1.x);
      float f0 = __expf(v0.x - mstar), f1 = __expf(v1.x - mstar);
      float inv = 1.0f / (v0.y * f0 + v1.y * f1);
#pragma unroll
      for (int ct = 0; ct < 4; ++ct) {
        f32x4 t0 = *(const f32x4*)(cb + g * 2176 + qq * 68 + ct * 16 + lg * 4);
        f32x4 t1 = *(const f32x4*)(cb + (g + 4) * 2176 + qq * 68 + ct * 16 + lg * 4);
        f32x4 o = f0 * t0 + f1 * t1;
#pragma unroll
        for (int rr = 0; rr < 4; ++rr) {
          int c = ct * 16 + lg * 4 + rr;
          size_t oi = ((size_t)(b * 64 + c)) * 4096 + nq;
          outp[oi] = g0 * (o[rr] * inv) + xres[oi];
        }
      }
    }
  }
}

// ---------------------------------------------------------------------------
extern "C" void kernel_launch(void* const* d_in, const int* in_sizes, int n_in,
                              void* d_out, int out_size, void* d_ws, size_t ws_size,
                              hipStream_t stream) {
  const float* x     = (const float*)d_in[0];
  const float* wq    = (const float*)d_in[1];
  const float* bq    = (const float*)d_in[2];
  const float* wQ    = (const float*)d_in[3];
  const float* bQ    = (const float*)d_in[4];
  const float* wK    = (const float*)d_in[5];
  const float* bK    = (const float*)d_in[6];
  const float* wV    = (const float*)d_in[7];
  const float* bV    = (const float*)d_in[8];
  const float* gamma = (const float*)d_in[9];

  __bf16* ws = (__bf16*)d_ws;
  __bf16* Kt = ws;
  __bf16* Vc = ws + 2097152;
  __bf16* Qt = ws + 4194304;
  __bf16* qt = ws + 6291456;
  __bf16* O1 = ws + 6815744;
  float*  partO  = (float*)((char*)d_ws + (16u << 20));
  float2* partML = (float2*)((char*)d_ws + (32u << 20));

  hipLaunchKernelGGL(conv4_kernel, dim3(1024), dim3(256), 0, stream,
                     x, wq, bq, wQ, bQ, wK, bK, wV, bV, Kt, Vc, Qt, qt);
  hipLaunchKernelGGL(attn1_kernel, dim3(256), dim3(512), 0, stream,
                     qt, Kt, Vc, partO, partML);
  hipLaunchKernelGGL(combine1_kernel, dim3(256), dim3(256), 0, stream,
                     partO, partML, O1);
  hipLaunchKernelGGL(attn2_kernel, dim3(256), dim3(512), 0, stream,
                     Qt, qt, O1, (float*)d_out, x, gamma);
}